// Round 7
// baseline (157.493 us; speedup 1.0000x reference)
//
#include <hip/hip_runtime.h>
#include <math.h>

// Problem constants (fixed by reference setup_inputs)
#define NN 8192
#define SS 32
#define DD 32
#define KK 1024
#define OUT_ELEMS ((size_t)NN * SS * DD)   // 8388608; loss scalar at out[OUT_ELEMS]

// loss = S * (1 + BETA) * sum_sq / (N*S*D)
#define LOSS_SCALE (32.0f * 1.001f / 8388608.0f)

typedef _Float16 half8  __attribute__((ext_vector_type(8)));
typedef float   floatx4 __attribute__((ext_vector_type(4)));

#define NTILES 64                      // 1024 codewords / 16 per MFMA tile
#define WAVES 16                       // 1024-thread blocks
#define BLK_ROWS (WAVES * 32)          // 512 rows per block (2 x 16 per wave)
#define NBLOCKS ((NN / BLK_ROWS) * SS) // 512 main blocks (1/CU, 2 rounds)

// f16 subnormal boundary / lo-term scaling (exact powers of 2)
#define FTZ16  6.103515625e-05f        // 2^-14
#define LSCALE 16384.0f                // 2^14: lo residuals -> normal f16 range
#define LDESC  6.103515625e-05f        // 2^-14: descale at the fp32 join

// SESSION NOTE (R13): R6-R12 = SIX schedule variants (lockstep dbuf, glload
// staging, LDS-resident barrier-free, manual SWP, 32x32 shape, asm-anchored
// counted-lgkmcnt pipeline) ALL land 85-95us @ MfmaUtil ~25%, insensitive to
// occupancy/barriers/ILP. No pipe saturated. Remaining shared factor: the
// OPERANDS. zl/bl lo-fragments of the hi/lo split are ~25-30% f16 SUBNORMAL
// for N(0,1) data -> every lo-term MFMA carries denormals; if the matrix
// pipe takes a denormal slow path (~4x), ALL schedules pin at ~25% of peak
// exactly as measured (and MOPS-derived MfmaUtil reads low, not high).
// Fix: scale lo fragments by 2^14 (exact) so they're normal f16; FTZ the hi
// part (residual moves to scaled lo); accumulate cross terms in a zero-C
// accumulator; join with one fmaf(t, 2^-14, h) per element. Same math,
// strictly better lo precision, chain depth 3->2.

// ---- workspace layout (d_ws): ~4.33 MB ----
#define W2P_OFF  4096                          // part[NBLOCKS] lives at 0
#define WP_OFF   (W2P_OFF + SS * KK * 4)       // w2P: 128 KB
// WP: [s][tile 0..63][H/L][lane 0..63][8 halves] = 128 KB per s, 4 MB total

typedef const __attribute__((address_space(1))) void* gas_p;
typedef __attribute__((address_space(3))) void* las_p;

__device__ __forceinline__ void gll16(const void* g, void* l) {
    __builtin_amdgcn_global_load_lds((gas_p)g, (las_p)l, 16, 0, 0);
}
__device__ __forceinline__ void gll4(const void* g, void* l) {
    __builtin_amdgcn_global_load_lds((gas_p)g, (las_p)l, 4, 0, 0);
}

#define MFMA16(a, b, c) __builtin_amdgcn_mfma_f32_16x16x32_f16((a), (b), (c), 0, 0, 0)

// ---- one-time W preprocessing: FTZ'd f16 hi + 2^14-scaled lo + row norms ----
// WP entry (s,g,{H,L},l) holds codeword k = g*16 + (l&15), dims d=(l>>4)*8..+7.
__global__ __launch_bounds__(256) void w_pre(const float* __restrict__ W,
                                             _Float16* __restrict__ WP,
                                             float* __restrict__ w2P) {
    const int u    = blockIdx.x * 256 + threadIdx.x;   // 0..131071
    const int s    = u >> 12;
    const int g    = (u >> 6) & 63;
    const int l    = u & 63;
    const int col  = l & 15;
    const int quad = l >> 4;
    const int k    = g * 16 + col;
    const float* src = W + ((size_t)s * KK + k) * DD + quad * 8;
    const float4 va = ((const float4*)src)[0];
    const float4 vb = ((const float4*)src)[1];
    const float v[8] = {va.x, va.y, va.z, va.w, vb.x, vb.y, vb.z, vb.w};
    half8 h8, l8; float ps = 0.0f;
    #pragma unroll
    for (int j = 0; j < 8; ++j) {
        const float x = v[j];
        ps = fmaf(x, x, ps);
        // FTZ hi: subnormal-range values go entirely to the (scaled) lo term
        const _Float16 h = (fabsf(x) < FTZ16) ? (_Float16)0.0f : (_Float16)x;
        h8[j] = h;
        l8[j] = (_Float16)((x - (float)h) * LSCALE);   // normal f16 now
    }
    ps += __shfl_xor(ps, 16, 64);
    ps += __shfl_xor(ps, 32, 64);
    _Float16* base = WP + ((size_t)(s * 64 + g) * 2) * 512;
    *(half8*)(base + l * 8) = h8;          // [g][H][l][8]
    *(half8*)(base + 512 + l * 8) = l8;    // [g][L][l][8]
    if (quad == 0) w2P[s * KK + k] = ps;
}

__global__ __launch_bounds__(1024, 4) void vq_fused(const float* __restrict__ z,
                                                    const float* __restrict__ W,
                                                    const _Float16* __restrict__ WP,
                                                    const float* __restrict__ w2P,
                                                    float* __restrict__ out,
                                                    float* __restrict__ part) {
    // Whole per-s codebook resident in LDS: 134.1 KB static (<160 KB).
    __shared__ _Float16 bufHL[NTILES][2][64][8];  // 128 KB  [tile][H/L][lane][8]
    __shared__ float    w2b[KK];                  // 4 KB
    __shared__ int      lds_idx[WAVES][32];       // 2 KB
    __shared__ float    lds_part[WAVES];

    const int s    = blockIdx.x & (SS - 1);
    const int n0b  = (blockIdx.x >> 5) * BLK_ROWS;
    const int tid  = threadIdx.x;
    const int wv   = tid >> 6;
    const int lane = tid & 63;
    const int col  = lane & 15;
    const int quad = lane >> 4;

    const float* __restrict__ Ws = W + (size_t)s * KK * DD;
    const int n0w = n0b + wv * 32;

    // ---- stage the whole codebook: 8 gll16 + 1 gll4 per wave ----
    // m104 rule: LDS dest = wave-uniform base; HW adds lane*16.
    {
        const char* gW = (const char*)(WP + (size_t)s * (NTILES * 2 * 512));
        char* lW = (char*)&bufHL[0][0][0][0];
        const int wvB = wv * 1024;             // 64 lanes * 16 B
        #pragma unroll
        for (int i = 0; i < 8; ++i) {
            const int off = i * 16384 + wvB;
            gll16(gW + off + lane * 16, lW + off);
        }
        const float* g2 = w2P + (size_t)s * KK + wv * 64;
        gll4(g2 + lane, (char*)w2b + wv * 256);
    }

    // ---- A-fragments: (-2*z), FTZ'd hi + scaled lo. A[m=col][d=quad*8+j]. ----
    half8 zh0, zl0, zh1, zl1;
    {
        const float* zp0 = z + (size_t)(n0w + col) * (SS * DD) + s * DD + quad * 8;
        const float* zp1 = zp0 + 16 * (SS * DD);
        const float4 va = ((const float4*)zp0)[0];
        const float4 vb = ((const float4*)zp0)[1];
        const float4 vc = ((const float4*)zp1)[0];
        const float4 vd = ((const float4*)zp1)[1];
        const float s0[8] = {va.x, va.y, va.z, va.w, vb.x, vb.y, vb.z, vb.w};
        const float s1[8] = {vc.x, vc.y, vc.z, vc.w, vd.x, vd.y, vd.z, vd.w};
        #pragma unroll
        for (int j = 0; j < 8; ++j) {
            const float v0 = -2.0f * s0[j];
            const _Float16 h0 = (fabsf(v0) < FTZ16) ? (_Float16)0.0f : (_Float16)v0;
            zh0[j] = h0; zl0[j] = (_Float16)((v0 - (float)h0) * LSCALE);
            const float v1 = -2.0f * s1[j];
            const _Float16 h1 = (fabsf(v1) < FTZ16) ? (_Float16)0.0f : (_Float16)v1;
            zh1[j] = h1; zl1[j] = (_Float16)((v1 - (float)h1) * LSCALE);
        }
    }

    floatx4 best0, best1;
    int bi0[4], bi1[4];
    best0 = best1 = (floatx4){INFINITY, INFINITY, INFINITY, INFINITY};
    bi0[0] = bi0[1] = bi0[2] = bi0[3] = 0;
    bi1[0] = bi1[1] = bi1[2] = bi1[3] = 0;

    __syncthreads();   // drains gll vmcnt; codebook visible

    // ---- K loop: 64 tiles. hi-term MFMA (c0=w2) + scaled cross-term MFMA
    // pair (zero-C), joined per element by one fmaf at compare time. ----
    const floatx4 zero4 = {0.0f, 0.0f, 0.0f, 0.0f};
    #pragma unroll 4
    for (int g = 0; g < NTILES; ++g) {
        const half8 bh = *(const half8*)&bufHL[g][0][lane][0];
        const half8 bl = *(const half8*)&bufHL[g][1][lane][0];
        const float w2v = w2b[g * 16 + col];
        const floatx4 c0 = {w2v, w2v, w2v, w2v};
        floatx4 h0 = MFMA16(zh0, bh, c0);       // w2 - 2 zh.w_h
        floatx4 h1 = MFMA16(zh1, bh, c0);
        floatx4 t0 = MFMA16(zl0, bh, zero4);    // 2^14 * (-2 zl.w_h)
        floatx4 t1 = MFMA16(zl1, bh, zero4);
        t0 = MFMA16(zh0, bl, t0);               // += 2^14 * (-2 zh.w_l)
        t1 = MFMA16(zh1, bl, t1);
        #pragma unroll
        for (int i = 0; i < 4; ++i) {   // strict <, lowest tile wins ties
            const float d0 = fmaf(t0[i], LDESC, h0[i]);
            const float d1 = fmaf(t1[i], LDESC, h1[i]);
            if (d0 < best0[i]) { best0[i] = d0; bi0[i] = g; }
            if (d1 < best1[i]) { best1[i] = d1; bi1[i] = g; }
        }
    }

    // ---- cross-lane argmin over the 16 k-columns; lower k wins ties ----
    #pragma unroll
    for (int i = 0; i < 4; ++i) {
        float v = best0[i];
        int   k = bi0[i] * 16 + col;
        #pragma unroll
        for (int m = 1; m < 16; m <<= 1) {
            const float vo = __shfl_xor(v, m, 64);
            const int   ko = __shfl_xor(k, m, 64);
            if (vo < v || (vo == v && ko < k)) { v = vo; k = ko; }
        }
        if (col == 0) lds_idx[wv][quad * 4 + i] = k;
    }
    #pragma unroll
    for (int i = 0; i < 4; ++i) {
        float v = best1[i];
        int   k = bi1[i] * 16 + col;
        #pragma unroll
        for (int m = 1; m < 16; m <<= 1) {
            const float vo = __shfl_xor(v, m, 64);
            const int   ko = __shfl_xor(k, m, 64);
            if (vo < v || (vo == v && ko < k)) { v = vo; k = ko; }
        }
        if (col == 0) lds_idx[wv][16 + quad * 4 + i] = k;
    }
    __syncthreads();

    // ---- epilogue: 2 lanes per n-row (16 floats each); zq = fp32 W[s,k*] ----
    const int r  = lane & 31;
    const int dh = (lane >> 5) * 16;
    const int krow = lds_idx[wv][r];
    const float* wsrc = Ws + (size_t)krow * DD + dh;
    const size_t zoff = (size_t)(n0w + r) * (SS * DD) + s * DD + dh;
    const float* zsrc = z + zoff;
    float* od = out + zoff;
    float sq = 0.0f;
    #pragma unroll
    for (int cc = 0; cc < 4; ++cc) {
        const float4 wq = ((const float4*)wsrc)[cc];
        const float4 zv = ((const float4*)zsrc)[cc];
        const float d0 = wq.x - zv.x, d1 = wq.y - zv.y;
        const float d2 = wq.z - zv.z, d3 = wq.w - zv.w;
        sq = fmaf(d0, d0, sq); sq = fmaf(d1, d1, sq);
        sq = fmaf(d2, d2, sq); sq = fmaf(d3, d3, sq);
        ((float4*)od)[cc] = wq;
    }
    #pragma unroll
    for (int off = 32; off > 0; off >>= 1) sq += __shfl_down(sq, off, 64);

    // per-block partial -> distinct address; NO same-address atomics
    if (lane == 0) lds_part[wv] = sq;
    __syncthreads();
    if (tid == 0) {
        float t = 0.0f;
        #pragma unroll
        for (int w = 0; w < WAVES; ++w) t += lds_part[w];
        part[blockIdx.x] = t;
    }
}

// Tiny final reduce: 1 block sums the per-block partials.
__global__ __launch_bounds__(256) void vq_loss(const float* __restrict__ part,
                                               float* __restrict__ out) {
    __shared__ float l[4];
    const int tid = threadIdx.x;
    float sum = 0.0f;
    #pragma unroll
    for (int i = 0; i < NBLOCKS / 256; ++i) sum += part[tid + i * 256];
    #pragma unroll
    for (int off = 32; off > 0; off >>= 1) sum += __shfl_down(sum, off, 64);
    if ((tid & 63) == 0) l[tid >> 6] = sum;
    __syncthreads();
    if (tid == 0) out[OUT_ELEMS] = (l[0] + l[1] + l[2] + l[3]) * LOSS_SCALE;
}

extern "C" void kernel_launch(void* const* d_in, const int* in_sizes, int n_in,
                              void* d_out, int out_size, void* d_ws, size_t ws_size,
                              hipStream_t stream) {
    const float* z = (const float*)d_in[0];   // (8192, 1024) fp32
    const float* W = (const float*)d_in[1];   // (32, 1024, 32) fp32
    float* out  = (float*)d_out;              // 8388608 zq_st + 1 loss

    char* ws = (char*)d_ws;                   // ~4.33 MB
    float*    part = (float*)ws;              // [0, 4KB)
    float*    w2P  = (float*)(ws + W2P_OFF);  // 128 KB
    _Float16* WP   = (_Float16*)(ws + WP_OFF); // 4 MB

    // one-time W split (4 MB read): 131072 threads
    w_pre<<<dim3(512), dim3(256), 0, stream>>>(W, WP, w2P);
    // 512 blocks: blockIdx&31 = s, blockIdx>>5 = 512-row n-tile.
    vq_fused<<<dim3(NBLOCKS), dim3(1024), 0, stream>>>(z, W, WP, w2P, out, part);
    vq_loss<<<dim3(1), dim3(256), 0, stream>>>(part, out);
}